// Round 6
// baseline (198.229 us; speedup 1.0000x reference)
//
#include <hip/hip_runtime.h>

// ShiftImgPreprocessor: out[b,t,c,i,j] = img[b,t,c, clamp(i+sy-4,0,95), clamp(j+sx-4,0,95)] / 255 - 0.5
//
// v5: persistent software-pipelined grid-stride.
// Evidence: v1(2 aligned loads,1out,NT)=58.6us; v2(unaligned,4out)=67.2;
// v3(aligned,4out)=66.8; v4(v1+plain store)=59. Load structure, MLP depth,
// and store policy ALL null -> per-tile instruction theories dead. The fill
// (6.8TB/s @ 9% occ) and m13 copy (6.29TB/s) are persistent grid-stride
// loops; all our versions were one-shot waves paying a full exposed memory
// latency + launch/drain per 3KB of traffic. v5 adopts the proven shape:
//  - 2048 blocks (8/CU, all co-resident; launch_bounds caps VGPR at 64),
//    each walks tiles x, x+2048, ... (13-14 tiles; no tail quantization).
//  - explicit 1-deep prefetch: tile k+1's loads issue BEFORE tile k's
//    blend+store, so the blend's waitcnt hits loads issued a whole tile ago;
//    each wave keeps ~2KB reads + 1KB writes continuously in flight.
//  - per-tile body = v1's verified math: two ALIGNED dwordx4 + wave-uniform
//    phase blend (r=dx&3, scalar branch); edge float4s fixed by the
//    uniform-dx swizzle table (verified in v2/v3 passing runs).
//  - b = tile/108 is block-uniform -> shift loads stay scalar (s_load).

#define PAD 4
#define NB  256
#define TT  4
#define CC  3
#define HH  96
#define WW  96
#define W4  (WW / 4)            // 24 float4 per row
#define TC  (TT * CC)           // 12 planes per batch
#define HW  (HH * WW)           // 9216 floats per plane
#define V4B (TC * HH * W4)      // 27648 float4 per batch
#define BLOCK 256
#define TPB (V4B / BLOCK)       // 108 tiles per batch
#define TILES (NB * TPB)        // 27648 tiles total
#define NBLK 2048               // 8 blocks/CU x 256 CU, all co-resident

typedef float vfloat4 __attribute__((ext_vector_type(4)));

__device__ __forceinline__ void stage_load(
    int tile, int tid,
    const float* __restrict__ img, const int* __restrict__ shift,
    float* __restrict__ out,
    vfloat4* A, vfloat4* B, int* s_, int* dx_, float** dst)
{
    const int b    = tile / TPB;          // block-uniform
    const int tloc = tile - b * TPB;      // [0, 108)
    const int vb   = tloc * BLOCK + tid;  // [0, V4B)
    const int j4   = vb % W4;
    const int r_   = vb / W4;
    const int i    = r_ % HH;
    const int tc   = r_ / HH;

    const int dx = shift[2 * b + 0] - PAD;   // [-4,4], uniform
    const int dy = shift[2 * b + 1] - PAD;
    const int yy = min(max(i + dy, 0), HH - 1);

    const size_t plane = ((size_t)b * TC + tc) * HW;
    const vfloat4* __restrict__ sv = (const vfloat4*)(img + plane + (size_t)yy * WW);

    const int j  = j4 * 4;
    const int s  = j + dx;                  // [-4, 96]
    const int a4 = s >> 2;                  // [-1, 24]
    const int a0 = min(max(a4, 0), W4 - 1);
    const int a1 = min(a4 + 1, W4 - 1);

    *A = sv[a0];                            // two aligned dwordx4, issued here,
    *B = sv[a1];                            // consumed a full tile later
    *s_  = s;
    *dx_ = dx;
    *dst = out + plane + (size_t)i * WW + j;
}

__device__ __forceinline__ void consume_store(
    vfloat4 A, vfloat4 B, int s, int dx, float* __restrict__ dst)
{
    vfloat4 o;
    switch (dx & 3) {                       // wave-uniform phase blend
        case 0:  o = A; break;
        case 1:  o = (vfloat4){A.y, A.z, A.w, B.x}; break;
        case 2:  o = (vfloat4){A.z, A.w, B.x, B.y}; break;
        default: o = (vfloat4){A.w, B.x, B.y, B.z}; break;
    }
    if (s < 0 || s > WW - 4) {              // edge float4: replicate-clamp
        switch (dx) {                       // uniform; o_k = A[clamp(dx+k,0,3)]
            case -4: o = (vfloat4){A.x, A.x, A.x, A.x}; break;
            case -3: o = (vfloat4){A.x, A.x, A.x, A.x}; break;
            case -2: o = (vfloat4){A.x, A.x, A.x, A.y}; break;
            case -1: o = (vfloat4){A.x, A.x, A.y, A.z}; break;
            case  1: o = (vfloat4){A.y, A.z, A.w, A.w}; break;
            case  2: o = (vfloat4){A.z, A.w, A.w, A.w}; break;
            default: o = (vfloat4){A.w, A.w, A.w, A.w}; break;   // dx=3,4
        }
    }
    o = o * (1.0f / 255.0f) - 0.5f;
    *(vfloat4*)dst = o;
}

__global__ __launch_bounds__(BLOCK, 8) void ShiftImgPreprocessor_36679020708143_kernel(
    const float* __restrict__ img,
    const int*   __restrict__ shift,
    float*       __restrict__ out)
{
    const int tid = threadIdx.x;
    int tile = blockIdx.x;                  // [0, NBLK) < TILES

    vfloat4 A0, B0; int s0, dx0; float* d0;
    stage_load(tile, tid, img, shift, out, &A0, &B0, &s0, &dx0, &d0);

    for (;;) {
        const int nt = tile + NBLK;
        if (nt < TILES) {
            // prefetch next tile BEFORE consuming current: its loads go into
            // flight under the current blend/store
            vfloat4 A1, B1; int s1, dx1; float* d1;
            stage_load(nt, tid, img, shift, out, &A1, &B1, &s1, &dx1, &d1);
            consume_store(A0, B0, s0, dx0, d0);
            A0 = A1; B0 = B1; s0 = s1; dx0 = dx1; d0 = d1;
            tile = nt;
        } else {
            consume_store(A0, B0, s0, dx0, d0);
            break;
        }
    }
}

extern "C" void kernel_launch(void* const* d_in, const int* in_sizes, int n_in,
                              void* d_out, int out_size, void* d_ws, size_t ws_size,
                              hipStream_t stream) {
    const float* img   = (const float*)d_in[0];
    const int*   shift = (const int*)d_in[1];
    float*       out   = (float*)d_out;

    ShiftImgPreprocessor_36679020708143_kernel<<<dim3(NBLK), BLOCK, 0, stream>>>(img, shift, out);
}

// Round 7
// 197.919 us; speedup vs baseline: 1.0016x; 1.0016x over previous
//
#include <hip/hip_runtime.h>

// ShiftImgPreprocessor: out[b,t,c,i,j] = img[b,t,c, clamp(i+sy-4,0,95), clamp(j+sx-4,0,95)] / 255 - 0.5
//
// v6: LDS-staged padded-row gather -> exactly 1.0x read amplification.
// History: v1 58.6us (2 aligned loads+blend), v2 67 (unaligned), v3 67
// (aligned,4out), v4 59 (plain store), v5 71 (persistent+prefetch; compiler
// collapsed the pipeline, VGPR=20). Accounting insight: v1's app-level bytes
// = 110MB*(1.67 reads) + 110MB writes = 293MB in 58.6us = 5.0 TB/s/CU-rate
// (8.1 B/cyc/CU) = 80% of m13's copy ceiling (10.2 B/cyc/CU). The residual
// inefficiency is the DUAL-load per output. v6 removes it:
//  - block(128 thr) = 16 rows of one (b,t,c) plane; stage 16 clamped input
//    rows into LDS as 104-float PADDED rows (pads = replicated edge pixels;
//    the LDS row IS the reference's replicate-padded row -> no edge cases).
//  - staging: aligned dwordx4 global loads (1.0x, fully coalesced) +
//    ds_write_b128 (even bank rotation, conflict-free).
//  - gather: 16B LDS read at byte offset 16+16c+4*dx (dx uniform in [-4,4],
//    4B-aligned, rotation-pattern conflict-free as b128; bounded ~3x on a
//    ~5us LDS budget if compiler splits to b32).
//  - store: aligned dwordx4, coalesced.
// Global traffic: exactly 1R+1W per element (223MB app); vmem instrs/output
// drop 2.67 -> 2. Prediction: kernel 42-48us, total ~177-184us.

#define PAD 4
#define NB  256
#define TT  4
#define CC  3
#define HH  96
#define WW  96
#define W4  (WW / 4)            // 24 float4 per row
#define TC  (TT * CC)           // 12 planes per batch
#define HW  (HH * WW)           // 9216 floats per plane
#define RPB 16                  // rows per block
#define BPP (HH / RPB)          // 6 row-blocks per plane
#define BLOCK 128
#define F4PB (RPB * W4)         // 384 float4 per block
#define PERT (F4PB / BLOCK)     // 3 per thread
#define LROW 104                // padded LDS row: 4 + 96 + 4 floats
#define NBLK (NB * TC * BPP)    // 18432 blocks

typedef float vfloat4 __attribute__((ext_vector_type(4)));

__global__ __launch_bounds__(BLOCK) void ShiftImgPreprocessor_36679020708143_kernel(
    const float* __restrict__ img,
    const int*   __restrict__ shift,
    float*       __restrict__ out)
{
    __shared__ float lds[RPB][LROW];

    const int blk = blockIdx.x;
    const int bp  = blk / BPP;          // plane id = b*TC + tc (block-uniform)
    const int rb  = blk - bp * BPP;     // row-block within plane
    const int b   = bp / TC;
    const int i0  = rb * RPB;           // first output row
    const int t   = threadIdx.x;

    // block-uniform -> scalar
    const int dx = shift[2 * b + 0] - PAD;   // [-4, 4]
    const int dy = shift[2 * b + 1] - PAD;

    const size_t plane = (size_t)bp * HW;
    const float* __restrict__ src = img + plane;
    float*       __restrict__ dst = out + plane;

    // ---- stage 16 clamped input rows into LDS (aligned, coalesced, 1.0x) ----
    #pragma unroll
    for (int p = 0; p < PERT; ++p) {
        const int u = t + p * BLOCK;        // [0, 384)
        const int k = u / W4;               // row slot [0,16)
        const int c = u - k * W4;           // float4 col [0,24)
        const int yy = min(max(i0 + k + dy, 0), HH - 1);
        const vfloat4 v = *(const vfloat4*)(src + (size_t)yy * WW + 4 * c);
        *(vfloat4*)&lds[k][4 + 4 * c] = v;  // 16B-aligned ds_write_b128
    }
    __syncthreads();

    // ---- fill replicate pads (LDS row becomes the reference padded row) ----
    if (t < RPB) {
        const float e = lds[t][4];          // col 0
        lds[t][0] = e; lds[t][1] = e; lds[t][2] = e; lds[t][3] = e;
    } else if (t < 2 * RPB) {
        const int k = t - RPB;
        const float e = lds[k][99];         // col 95
        lds[k][100] = e; lds[k][101] = e; lds[k][102] = e; lds[k][103] = e;
    }
    __syncthreads();

    // ---- gather at uniform shift dx, scale, store (aligned, coalesced) ----
    const float kk = 1.0f / 255.0f;
    #pragma unroll
    for (int p = 0; p < PERT; ++p) {
        const int u = t + p * BLOCK;
        const int k = u / W4;
        const int c = u - k * W4;
        // padded-row read: floats [4 + 4c + dx .. +3], byte offset 4B-aligned
        const float* lp = &lds[k][0] + (4 + 4 * c + dx);
        vfloat4 v;
        __builtin_memcpy(&v, lp, sizeof(v));    // LDS: misalignment is cheap
        v = v * kk - 0.5f;
        *(vfloat4*)(dst + (size_t)(i0 + k) * WW + 4 * c) = v;
    }
}

extern "C" void kernel_launch(void* const* d_in, const int* in_sizes, int n_in,
                              void* d_out, int out_size, void* d_ws, size_t ws_size,
                              hipStream_t stream) {
    const float* img   = (const float*)d_in[0];
    const int*   shift = (const int*)d_in[1];
    float*       out   = (float*)d_out;

    ShiftImgPreprocessor_36679020708143_kernel<<<dim3(NBLK), BLOCK, 0, stream>>>(img, shift, out);
}